// Round 1
// baseline (10.206 us; speedup 1.0000x reference)
//
#include <hip/hip_runtime.h>
#include <math.h>

// Problem constants (from reference setup_inputs): x [B=4, C=3, H=256, W=256] f32
// REGION_SIZE = 3, BANDWIDTH = 0.5 -> logits = -d2/(2*h*h) = -2*d2
// out[b,i,j] = log(9) + 3*log(sqrt(2pi)*0.5) - (1/9) * sum_n log( sum_m exp(-2*d2[n][m]) )

#define RS 3
#define NP 9           // RS*RS
#define CC 3

__global__ __launch_bounds__(256) void je_kernel(const float* __restrict__ x,
                                                 float* __restrict__ out,
                                                 int B, int H, int W) {
    const int Hp = H - RS + 1;
    const int Wp = W - RS + 1;
    const int total = B * Hp * Wp;
    int tid = blockIdx.x * blockDim.x + threadIdx.x;
    if (tid >= total) return;

    const int j = tid % Wp;
    int t = tid / Wp;
    const int i = t % Hp;
    const int b = t / Hp;

    // Load 3x3x3 patch: p[n][c], n = di*3+dj
    float p[NP][CC];
    const float* xb = x + (size_t)b * CC * H * W;
#pragma unroll
    for (int c = 0; c < CC; ++c) {
        const float* xc = xb + (size_t)c * H * W;
#pragma unroll
        for (int di = 0; di < RS; ++di) {
            const float* row = xc + (size_t)(i + di) * W + j;
#pragma unroll
            for (int dj = 0; dj < RS; ++dj) {
                p[di * RS + dj][c] = row[dj];
            }
        }
    }

    // s[n] = sum_m exp(-2*d2[n][m]); diagonal contributes exp(0)=1
    float s[NP];
#pragma unroll
    for (int n = 0; n < NP; ++n) s[n] = 1.0f;

#pragma unroll
    for (int n = 0; n < NP; ++n) {
#pragma unroll
        for (int m = n + 1; m < NP; ++m) {
            float d0 = p[n][0] - p[m][0];
            float d1 = p[n][1] - p[m][1];
            float d2 = p[n][2] - p[m][2];
            float dd = d0 * d0 + d1 * d1 + d2 * d2;
            float e = __expf(-2.0f * dd);
            s[n] += e;
            s[m] += e;
        }
    }

    float acc = 0.0f;
#pragma unroll
    for (int n = 0; n < NP; ++n) acc += __logf(s[n]);

    // log(9) + 3*log(sqrt(2*pi)*0.5)
    const float cst = 2.8745986353f;
    out[tid] = cst - acc * (1.0f / 9.0f);
}

extern "C" void kernel_launch(void* const* d_in, const int* in_sizes, int n_in,
                              void* d_out, int out_size, void* d_ws, size_t ws_size,
                              hipStream_t stream) {
    const float* x = (const float*)d_in[0];
    float* out = (float*)d_out;

    const int B = 4, C = 3, H = 256, W = 256;
    (void)C;
    const int Hp = H - RS + 1, Wp = W - RS + 1;
    const int total = B * Hp * Wp;   // == out_size
    const int block = 256;
    const int grid = (total + block - 1) / block;
    je_kernel<<<grid, block, 0, stream>>>(x, out, B, H, W);
}